// Round 9
// baseline (580.041 us; speedup 1.0000x reference)
//
#include <hip/hip_runtime.h>
#include <stdint.h>

typedef __attribute__((ext_vector_type(8))) short bf16x8;
typedef __attribute__((ext_vector_type(4))) float f32x4;
typedef __attribute__((ext_vector_type(8))) unsigned short us8;
typedef __bf16 bf16v2 __attribute__((ext_vector_type(2)));

#define T_CNT 1048576
#define E_CNT 262144

static __device__ __forceinline__ unsigned short f2bf_u(float f) {
  __bf16 h = (__bf16)f;
  return __builtin_bit_cast(unsigned short, h);
}
// pair-cast -> compiler emits v_cvt_pk_bf16_f32
static __device__ __forceinline__ uint32_t pack2bf(float a, float b) {
  bf16v2 t; t[0] = (__bf16)a; t[1] = (__bf16)b;
  return __builtin_bit_cast(uint32_t, t);
}
static __device__ __forceinline__ float silu_f(float v) {
  float e = __builtin_amdgcn_exp2f(v * -1.44269504088896341f);
  return v * __builtin_amdgcn_rcpf(1.0f + e);
}
static __device__ __forceinline__ bf16x8 frag8(f32x4 a, f32x4 b) {
  union { bf16x8 v; uint32_t u[4]; } r;
  r.u[0] = pack2bf(a[0], a[1]); r.u[1] = pack2bf(a[2], a[3]);
  r.u[2] = pack2bf(b[0], b[1]); r.u[3] = pack2bf(b[2], b[3]);
  return r.v;
}

// ---------------------------------------------------------------------------
// R9: 128-thread blocks (2 waves), 32-row tiles, 16KB LDS -> 10 blocks/CU
// (20 waves/CU of independent streams; TLP is the latency-hiding mechanism).
// Wave w owns cols [w*64, w*64+64) (4 ct slices). Layer loop is ks-outer:
// acc[2][4] (32 regs) + 4 transient weight frags (16) -> fits the 64-VGPR
// allocation the compiler insists on. Weights stream from L2-hot ws frags.
// ---------------------------------------------------------------------------
template<bool LAST>
static __device__ __forceinline__ void layer_mfma(
    const char* __restrict__ src, char* __restrict__ dst,
    const char* __restrict__ wbase,  // wt4 + L*32768
    const float* __restrict__ bias,  // nullptr for LAST
    float* __restrict__ gout,        // out + tb*128 for LAST
    int l15, int q, int w, int rs)
{
  f32x4 acc[2][4];
  #pragma unroll
  for (int rg = 0; rg < 2; ++rg)
    #pragma unroll
    for (int c = 0; c < 4; ++c) { f32x4 z = {0.f,0.f,0.f,0.f}; acc[rg][c] = z; }

  const int lane16 = (l15 | (q << 4)) * 16;
  #pragma unroll
  for (int ks = 0; ks < 4; ++ks) {
    bf16x8 wf[4];
    #pragma unroll
    for (int c = 0; c < 4; ++c)
      wf[c] = *(const bf16x8*)(wbase + (((w * 4 + c) * 4 + ks) << 10) + lane16);
    bf16x8 xf0 = *(const bf16x8*)(src + ((l15 * 256 + ks * 64 + q * 16) ^ rs));
    bf16x8 xf1 = *(const bf16x8*)(src + (((16 + l15) * 256 + ks * 64 + q * 16) ^ rs));
    #pragma unroll
    for (int c = 0; c < 4; ++c) {
      acc[0][c] = __builtin_amdgcn_mfma_f32_16x16x32_bf16(wf[c], xf0, acc[0][c], 0, 0, 0);
      acc[1][c] = __builtin_amdgcn_mfma_f32_16x16x32_bf16(wf[c], xf1, acc[1][c], 0, 0, 0);
    }
  }

  #pragma unroll
  for (int rg = 0; rg < 2; ++rg) {
    const int row = rg * 16 + l15;
    #pragma unroll
    for (int c = 0; c < 4; ++c) {
      if (!LAST) {
        f32x4 bv = *(const f32x4*)(bias + w * 64 + c * 16 + q * 4);
        uint2 u;
        u.x = pack2bf(silu_f(acc[rg][c][0] + bv[0]), silu_f(acc[rg][c][1] + bv[1]));
        u.y = pack2bf(silu_f(acc[rg][c][2] + bv[2]), silu_f(acc[rg][c][3] + bv[3]));
        *(uint2*)(dst + ((row * 256 + w * 128 + c * 32 + q * 8) ^ rs)) = u;
      } else {
        __builtin_nontemporal_store(acc[rg][c],
            (f32x4*)(gout + (size_t)row * 128 + w * 64 + c * 16 + q * 4));
      }
    }
  }
}

__global__ __launch_bounds__(128)
__attribute__((amdgpu_waves_per_eu(4, 5)))
void angle_kernel(
    const float* __restrict__ m_ji, const float* __restrict__ a_sbf,
    const int* __restrict__ kj, const int* __restrict__ ji,
    const float* __restrict__ b1, const float* __restrict__ b2,
    const float* __restrict__ b3,
    const char* __restrict__ wt4, const char* __restrict__ waT,
    float* __restrict__ out)
{
  __shared__ __align__(16) char xbA[8192];
  __shared__ __align__(16) char xbB[8192];
  const int tid = threadIdx.x, lane = tid & 63, w = tid >> 6;
  const int l15 = lane & 15, q = lane >> 4;
  const int rs = (l15 & 7) << 4;
  const size_t tb = (size_t)blockIdx.x * 32;
  const int lane16 = lane * 16;

  // proj + gather-gate -> x0 -> xbA (plain per-use loads; TLP hides latency)
  #pragma unroll
  for (int rg = 0; rg < 2; ++rg) {
    const int row = rg * 16 + l15;
    const size_t grow = tb + row;
    const int ikj = kj[grow], iji = ji[grow];
    const float* ap = a_sbf + grow * 42;
    f32x4 a0 = *(const f32x4*)(ap + q * 8);
    f32x4 a1 = *(const f32x4*)(ap + q * 8 + 4);
    f32x4 c0 = {0.f,0.f,0.f,0.f}, c1 = {0.f,0.f,0.f,0.f};
    if (q == 0) { c0 = *(const f32x4*)(ap + 32); c1 = *(const f32x4*)(ap + 36); }
    else if (q == 1) { float2 t = *(const float2*)(ap + 40); c0[0] = t.x; c0[1] = t.y; }
    bf16x8 f0 = frag8(a0, a1);
    bf16x8 f1 = frag8(c0, c1);
    #pragma unroll
    for (int c = 0; c < 4; ++c) {
      const int ct = w * 4 + c;
      bf16x8 wa0 = *(const bf16x8*)(waT + ((ct * 2 + 0) << 10) + lane16);
      bf16x8 wa1 = *(const bf16x8*)(waT + ((ct * 2 + 1) << 10) + lane16);
      f32x4 acc = {0.f,0.f,0.f,0.f};
      acc = __builtin_amdgcn_mfma_f32_16x16x32_bf16(wa0, f0, acc, 0, 0, 0);
      acc = __builtin_amdgcn_mfma_f32_16x16x32_bf16(wa1, f1, acc, 0, 0, 0);
      const float* bk = m_ji + (size_t)ikj * 128 + ct * 16 + q * 4;
      const float* bj = m_ji + (size_t)iji * 128 + ct * 16 + q * 4;
      f32x4 pk = *(const f32x4*)(bk);
      f32x4 pj = *(const f32x4*)(bj);
      f32x4 g = pk + pj;
      uint2 u;
      u.x = pack2bf(acc[0] * g[0], acc[1] * g[1]);
      u.y = pack2bf(acc[2] * g[2], acc[3] * g[3]);
      *(uint2*)(xbA + ((row * 256 + w * 128 + c * 32 + q * 8) ^ rs)) = u;
    }
  }
  __syncthreads();

  layer_mfma<false>(xbA, xbB, wt4,           b1, nullptr, l15, q, w, rs);
  __syncthreads();
  layer_mfma<false>(xbB, xbA, wt4 + 32768,   b2, nullptr, l15, q, w, rs);
  __syncthreads();
  layer_mfma<false>(xbA, xbB, wt4 + 65536,   b3, nullptr, l15, q, w, rs);
  __syncthreads();
  layer_mfma<true >(xbB, nullptr, wt4 + 98304, nullptr,
                    out + tb * 128, l15, q, w, rs);
}

__global__ __launch_bounds__(128)
__attribute__((amdgpu_waves_per_eu(4, 5)))
void edge_kernel(
    const float* __restrict__ m_ji, const float* __restrict__ e_rbf,
    const float* __restrict__ b1, const float* __restrict__ b2,
    const float* __restrict__ b3,
    const char* __restrict__ wt4, const char* __restrict__ weT,
    float* __restrict__ out)
{
  __shared__ __align__(16) char xbA[8192];
  __shared__ __align__(16) char xbB[8192];
  const int tid = threadIdx.x, lane = tid & 63, w = tid >> 6;
  const int l15 = lane & 15, q = lane >> 4;
  const int rs = (l15 & 7) << 4;
  const size_t tb = (size_t)blockIdx.x * 32;
  const int lane16 = lane * 16;

  #pragma unroll
  for (int rg = 0; rg < 2; ++rg) {
    const int row = rg * 16 + l15;
    const size_t grow = tb + row;
    const float* ep = e_rbf + grow * 6;
    f32x4 a0 = {0.f,0.f,0.f,0.f}, a1 = {0.f,0.f,0.f,0.f};
    if (q == 0) {
      a0 = *(const f32x4*)(ep);
      float2 t = *(const float2*)(ep + 4);
      a1[0] = t.x; a1[1] = t.y;
    }
    bf16x8 ef = frag8(a0, a1);
    #pragma unroll
    for (int c = 0; c < 4; ++c) {
      const int ct = w * 4 + c;
      bf16x8 we = *(const bf16x8*)(weT + (ct << 10) + lane16);
      f32x4 acc = {0.f,0.f,0.f,0.f};
      acc = __builtin_amdgcn_mfma_f32_16x16x32_bf16(we, ef, acc, 0, 0, 0);
      f32x4 g = *(const f32x4*)(m_ji + grow * 128 + ct * 16 + q * 4);
      uint2 u;
      u.x = pack2bf(acc[0] * g[0], acc[1] * g[1]);
      u.y = pack2bf(acc[2] * g[2], acc[3] * g[3]);
      *(uint2*)(xbA + ((row * 256 + w * 128 + c * 32 + q * 8) ^ rs)) = u;
    }
  }
  __syncthreads();

  layer_mfma<false>(xbA, xbB, wt4,           b1, nullptr, l15, q, w, rs);
  __syncthreads();
  layer_mfma<false>(xbB, xbA, wt4 + 32768,   b2, nullptr, l15, q, w, rs);
  __syncthreads();
  layer_mfma<false>(xbA, xbB, wt4 + 65536,   b3, nullptr, l15, q, w, rs);
  __syncthreads();
  layer_mfma<true >(xbB, nullptr, wt4 + 98304, nullptr,
                    out + tb * 128, l15, q, w, rs);
}

// ---------------------------------------------------------------------------
// Prep: bf16 weights into fragment-linear layouts in d_ws (unchanged layout).
//  [0,128K):    edge W1..W4 frags [mat][ct*4+ks][lane]16B
//  [128K,256K): angle W1..W4 frags
//  [256K,272K): Wa proj frags [ct*2+ks][lane]  (K pad 42->64)
//  [272K,276K): We proj frags [ct][lane]       (K pad 6->32)
// frag(lane; n = ct*16+l15, k = ks*32+q*8+j) = W[k][n]
// ---------------------------------------------------------------------------
__global__ void prep_kernel(
    const float* __restrict__ W0, const float* __restrict__ W1,
    const float* __restrict__ W2, const float* __restrict__ W3,
    const float* __restrict__ W4, const float* __restrict__ W5,
    const float* __restrict__ W6, const float* __restrict__ W7,
    const float* __restrict__ Wa, const float* __restrict__ We,
    char* __restrict__ ws)
{
  const int gid = blockIdx.x * 256 + threadIdx.x;
  const int lane = gid & 63;
  const int l15 = lane & 15, q = lane >> 4;
  if (gid < 16384) {
    const int mat = gid >> 11;
    const int ctks = (gid & 2047) >> 6;
    const int n = (ctks >> 2) * 16 + l15;
    const int k0 = (ctks & 3) * 32 + q * 8;
    const float* W;
    switch (mat) {
      case 0: W = W0; break; case 1: W = W1; break;
      case 2: W = W2; break; case 3: W = W3; break;
      case 4: W = W4; break; case 5: W = W5; break;
      case 6: W = W6; break; default: W = W7; break;
    }
    us8 v;
    #pragma unroll
    for (int j = 0; j < 8; ++j) v[j] = f2bf_u(W[(size_t)(k0 + j) * 128 + n]);
    *(us8*)(ws + mat * 32768 + ctks * 1024 + lane * 16) = v;
  } else if (gid < 17408) {
    const int g = gid - 16384;
    const int ctks = g >> 6;
    const int n = (ctks >> 1) * 16 + l15;
    const int k0 = (ctks & 1) * 32 + q * 8;
    us8 v;
    #pragma unroll
    for (int j = 0; j < 8; ++j) {
      const int k = k0 + j;
      v[j] = (k < 42) ? f2bf_u(Wa[(size_t)k * 128 + n]) : (unsigned short)0;
    }
    *(us8*)(ws + 262144 + ctks * 1024 + lane * 16) = v;
  } else if (gid < 17920) {
    const int g = gid - 17408;
    const int ct = g >> 6;
    const int n = ct * 16 + l15;
    const int k0 = q * 8;
    us8 v;
    #pragma unroll
    for (int j = 0; j < 8; ++j) {
      const int k = k0 + j;
      v[j] = (k < 6) ? f2bf_u(We[(size_t)k * 128 + n]) : (unsigned short)0;
    }
    *(us8*)(ws + 278528 + ct * 1024 + lane * 16) = v;
  }
}

extern "C" void kernel_launch(void* const* d_in, const int* in_sizes, int n_in,
                              void* d_out, int out_size, void* d_ws, size_t ws_size,
                              hipStream_t stream) {
  (void)in_sizes; (void)n_in; (void)out_size; (void)ws_size;
  const float* m_ji  = (const float*)d_in[0];
  const float* e_rbf = (const float*)d_in[1];
  const float* a_sbf = (const float*)d_in[2];
  const int*   kj    = (const int*)d_in[4];
  const int*   ji    = (const int*)d_in[5];
  const float* We    = (const float*)d_in[6];
  const float* We1   = (const float*)d_in[7];
  const float* be1   = (const float*)d_in[8];
  const float* We2   = (const float*)d_in[9];
  const float* be2   = (const float*)d_in[10];
  const float* We3   = (const float*)d_in[11];
  const float* be3   = (const float*)d_in[12];
  const float* We4   = (const float*)d_in[13];
  const float* Wa    = (const float*)d_in[14];
  const float* Wa1   = (const float*)d_in[15];
  const float* ba1   = (const float*)d_in[16];
  const float* Wa2   = (const float*)d_in[17];
  const float* ba2   = (const float*)d_in[18];
  const float* Wa3   = (const float*)d_in[19];
  const float* ba3   = (const float*)d_in[20];
  const float* Wa4   = (const float*)d_in[21];
  char* ws = (char*)d_ws;
  float* out = (float*)d_out;

  prep_kernel<<<70, 256, 0, stream>>>(
      We1, We2, We3, We4, Wa1, Wa2, Wa3, Wa4, Wa, We, ws);
  edge_kernel<<<E_CNT / 32, 128, 0, stream>>>(
      m_ji, e_rbf, be1, be2, be3, ws, ws + 278528, out);
  angle_kernel<<<T_CNT / 32, 128, 0, stream>>>(
      m_ji, a_sbf, kj, ji, ba1, ba2, ba3, ws + 131072, ws + 262144,
      out + (size_t)E_CNT * 128);
}